// Round 1
// baseline (2420.953 us; speedup 1.0000x reference)
//
#include <hip/hip_runtime.h>
#include <math.h>

#define NN 100000
#define NE 625000
#define CC 128

// ---------------- degree / inverse ----------------

__global__ void degree_kernel(const int* __restrict__ dst, float* __restrict__ cnt) {
    int e = blockIdx.x * blockDim.x + threadIdx.x;
    if (e < NE) atomicAdd(&cnt[dst[e]], 1.0f);
}

__global__ void inv_kernel(float* __restrict__ cnt) {
    int i = blockIdx.x * blockDim.x + threadIdx.x;
    if (i < NN) cnt[i] = 1.0f / fmaxf(cnt[i], 1.0f);
}

// ---------------- edge scatter: agg[dst] += feat[src] ----------------
// 32 threads per edge, float4 per thread. Grid sized exactly: NE*32/256 blocks.

__global__ void scatter_kernel(const float* __restrict__ feat,
                               const int* __restrict__ src,
                               const int* __restrict__ dst,
                               float* __restrict__ agg) {
    int gtid = blockIdx.x * blockDim.x + threadIdx.x;
    int e    = gtid >> 5;
    int lane = gtid & 31;
    int c    = lane * 4;
    int s = src[e];
    int d = dst[e];
    float4 v = *(const float4*)&feat[(size_t)s * CC + c];
    float* p = &agg[(size_t)d * CC + c];
    atomicAdd(p + 0, v.x);
    atomicAdd(p + 1, v.y);
    atomicAdd(p + 2, v.z);
    atomicAdd(p + 3, v.w);
}

// ---------------- fused SAGE GEMM ----------------
// out[i][c] = act( inv[i] * dot(agg[i], Wl[c]) + dot(feat[i], Wr[c]) + b[c] )
// Treated as K=256 concat GEMM; inv folded into A-staging for k<128.
// Block: 256 threads, 32 rows x 128 cols, 4x4 register tile per thread.

template<bool SIGMOID>
__global__ void sage_gemm_kernel(const float* __restrict__ agg,
                                 const float* __restrict__ feat,
                                 const float* __restrict__ inv,
                                 const float* __restrict__ Wl,
                                 const float* __restrict__ Wr,
                                 const float* __restrict__ bias,
                                 float* __restrict__ out) {
    constexpr int ROWS = 32;
    constexpr int CK   = 32;
    __shared__ float At[CK][ROWS + 4];   // stride 36 (16B-aligned rows)
    __shared__ float Wt[CK][CC + 4];     // stride 132

    const int t    = threadIdx.x;
    const int row0 = blockIdx.x * ROWS;

    const int tr = t >> 5;   // 0..7  (row group of 4)
    const int tc = t & 31;   // 0..31 (col group of 4)

    // staging mapping for A: 32 rows x 8 k-quads
    const int sr = t >> 3;   // 0..31
    const int sq = t & 7;    // 0..7

    const float invr = inv[row0 + sr];

    float acc[4][4];
#pragma unroll
    for (int i = 0; i < 4; ++i)
#pragma unroll
        for (int j = 0; j < 4; ++j) acc[i][j] = 0.0f;

    for (int kc = 0; kc < 256; kc += CK) {
        const bool first = (kc < 128);
        const float* Asrc = first ? agg : feat;
        const float* Wsrc = first ? Wl  : Wr;
        const int kb = first ? kc : (kc - 128);

        // stage A chunk (transposed), scale agg part by inv[row]
        float4 av = *(const float4*)&Asrc[(size_t)(row0 + sr) * CC + kb + sq * 4];
        if (first) { av.x *= invr; av.y *= invr; av.z *= invr; av.w *= invr; }
        At[sq * 4 + 0][sr] = av.x;
        At[sq * 4 + 1][sr] = av.y;
        At[sq * 4 + 2][sr] = av.z;
        At[sq * 4 + 3][sr] = av.w;

        // stage W chunk transposed: Wt[k][c] = Wsrc[c][kb+k]
#pragma unroll
        for (int j = 0; j < 4; ++j) {
            int lin = t + j * 256;        // 0..1023
            int c   = lin >> 3;           // 0..127
            int q   = lin & 7;            // 0..7
            float4 wv = *(const float4*)&Wsrc[c * CC + kb + q * 4];
            Wt[q * 4 + 0][c] = wv.x;
            Wt[q * 4 + 1][c] = wv.y;
            Wt[q * 4 + 2][c] = wv.z;
            Wt[q * 4 + 3][c] = wv.w;
        }
        __syncthreads();

#pragma unroll
        for (int kk = 0; kk < CK; ++kk) {
            float4 a = *(const float4*)&At[kk][tr * 4];
            float4 w = *(const float4*)&Wt[kk][tc * 4];
            acc[0][0] += a.x * w.x; acc[0][1] += a.x * w.y; acc[0][2] += a.x * w.z; acc[0][3] += a.x * w.w;
            acc[1][0] += a.y * w.x; acc[1][1] += a.y * w.y; acc[1][2] += a.y * w.z; acc[1][3] += a.y * w.w;
            acc[2][0] += a.z * w.x; acc[2][1] += a.z * w.y; acc[2][2] += a.z * w.z; acc[2][3] += a.z * w.w;
            acc[3][0] += a.w * w.x; acc[3][1] += a.w * w.y; acc[3][2] += a.w * w.z; acc[3][3] += a.w * w.w;
        }
        __syncthreads();
    }

    // epilogue: bias (+ sigmoid), write 4 rows x 4 cols
    const float4 bv = *(const float4*)&bias[tc * 4];
#pragma unroll
    for (int i = 0; i < 4; ++i) {
        const int r = row0 + tr * 4 + i;
        float4 o;
        o.x = acc[i][0] + bv.x;
        o.y = acc[i][1] + bv.y;
        o.z = acc[i][2] + bv.z;
        o.w = acc[i][3] + bv.w;
        if (SIGMOID) {
            o.x = 1.0f / (1.0f + __expf(-o.x));
            o.y = 1.0f / (1.0f + __expf(-o.y));
            o.z = 1.0f / (1.0f + __expf(-o.z));
            o.w = 1.0f / (1.0f + __expf(-o.w));
        }
        *(float4*)&out[(size_t)r * CC + tc * 4] = o;
    }
}

// ---------------- launch ----------------

extern "C" void kernel_launch(void* const* d_in, const int* in_sizes, int n_in,
                              void* d_out, int out_size, void* d_ws, size_t ws_size,
                              hipStream_t stream) {
    const float* x   = (const float*)d_in[0];
    const int*   ei  = (const int*)d_in[1];
    const float* W1l = (const float*)d_in[2];
    const float* b1l = (const float*)d_in[3];
    const float* W1r = (const float*)d_in[4];
    const float* W2l = (const float*)d_in[5];
    const float* b2l = (const float*)d_in[6];
    const float* W2r = (const float*)d_in[7];
    float* out = (float*)d_out;

    const int* src = ei;        // edge_index[0]
    const int* dst = ei + NE;   // edge_index[1]

    float* inv = (float*)d_ws;                 // NN floats (first holds counts)
    float* agg = inv + NN;                     // NN*CC floats
    float* h   = out;                          // layer-1 activations live in d_out

    // zero count + agg
    hipMemsetAsync(d_ws, 0, (size_t)(NN + (size_t)NN * CC) * sizeof(float), stream);

    degree_kernel<<<(NE + 255) / 256, 256, 0, stream>>>(dst, inv);
    inv_kernel<<<(NN + 255) / 256, 256, 0, stream>>>(inv);

    // layer 1
    scatter_kernel<<<(NE * 32) / 256, 256, 0, stream>>>(x, src, dst, agg);
    sage_gemm_kernel<true><<<NN / 32, 256, 0, stream>>>(agg, x, inv, W1l, W1r, b1l, h);

    // layer 2
    hipMemsetAsync(agg, 0, (size_t)NN * CC * sizeof(float), stream);
    scatter_kernel<<<(NE * 32) / 256, 256, 0, stream>>>(h, src, dst, agg);
    sage_gemm_kernel<false><<<NN / 32, 256, 0, stream>>>(agg, h, inv, W2l, W2r, b2l, out);
}

// Round 2
// 678.458 us; speedup vs baseline: 3.5683x; 3.5683x over previous
//
#include <hip/hip_runtime.h>
#include <math.h>

#define NN 100000
#define NE 625000
#define CC 128

// ---------------- CSR build ----------------

__global__ void degree_kernel(const int* __restrict__ dst, int* __restrict__ cnt) {
    int e = blockIdx.x * blockDim.x + threadIdx.x;
    if (e < NE) atomicAdd(&cnt[dst[e]], 1);
}

// single-block exclusive scan of cnt[NN] -> rowptr[NN+1]
__global__ __launch_bounds__(1024) void scan_kernel(const int* __restrict__ cnt,
                                                    int* __restrict__ rowptr) {
    __shared__ int part[1024];
    const int t = threadIdx.x;
    const int CHUNK = (NN + 1023) / 1024;   // 98
    int beg = t * CHUNK;
    int end = beg + CHUNK; if (end > NN) end = NN;
    int s = 0;
    for (int i = beg; i < end; ++i) s += cnt[i];
    part[t] = s;
    __syncthreads();
    for (int off = 1; off < 1024; off <<= 1) {
        int v = (t >= off) ? part[t - off] : 0;
        __syncthreads();
        part[t] += v;
        __syncthreads();
    }
    int run = (t == 0) ? 0 : part[t - 1];
    for (int i = beg; i < end; ++i) { rowptr[i] = run; run += cnt[i]; }
    if (t == 1023) rowptr[NN] = run;
}

__global__ void fill_kernel(const int* __restrict__ src, const int* __restrict__ dst,
                            const int* __restrict__ rowptr, int* __restrict__ cursor,
                            int* __restrict__ col) {
    int e = blockIdx.x * blockDim.x + threadIdx.x;
    if (e < NE) {
        int d = dst[e];
        int p = atomicAdd(&cursor[d], 1);
        col[rowptr[d] + p] = src[e];
    }
}

__global__ void inv_kernel(const int* __restrict__ rowptr, float* __restrict__ inv) {
    int i = blockIdx.x * blockDim.x + threadIdx.x;
    if (i < NN) {
        int d = rowptr[i + 1] - rowptr[i];
        inv[i] = 1.0f / (float)(d > 0 ? d : 1);
    }
}

// ---------------- gather-aggregate: agg[n] = inv[n] * sum_{j in nbr(n)} feat[col[j]] ----
// one wave (64 lanes) per node, float2 per lane.

__global__ void gather_kernel(const float* __restrict__ feat,
                              const int* __restrict__ rowptr,
                              const int* __restrict__ col,
                              const float* __restrict__ inv,
                              float* __restrict__ agg) {
    int gtid = blockIdx.x * blockDim.x + threadIdx.x;
    int node = gtid >> 6;
    int lane = (gtid & 63) * 2;
    if (node >= NN) return;
    int beg = rowptr[node], end = rowptr[node + 1];
    float sx = 0.0f, sy = 0.0f;
    for (int j = beg; j < end; ++j) {
        int s = col[j];
        float2 v = *(const float2*)&feat[(size_t)s * CC + lane];
        sx += v.x; sy += v.y;
    }
    float iv = inv[node];
    float2 o; o.x = sx * iv; o.y = sy * iv;
    *(float2*)&agg[(size_t)node * CC + lane] = o;
}

// ---------------- fused SAGE GEMM ----------------
// out[i][c] = act( dot(agg[i], Wl[c]) + dot(feat[i], Wr[c]) + b[c] )
// (inv already folded into agg by gather). K=256 concat GEMM.

template<bool SIGMOID>
__global__ void sage_gemm_kernel(const float* __restrict__ agg,
                                 const float* __restrict__ feat,
                                 const float* __restrict__ Wl,
                                 const float* __restrict__ Wr,
                                 const float* __restrict__ bias,
                                 float* __restrict__ out) {
    constexpr int ROWS = 32;
    constexpr int CK   = 32;
    __shared__ float At[CK][ROWS + 4];
    __shared__ float Wt[CK][CC + 4];

    const int t    = threadIdx.x;
    const int row0 = blockIdx.x * ROWS;

    const int tr = t >> 5;
    const int tc = t & 31;
    const int sr = t >> 3;
    const int sq = t & 7;

    float acc[4][4];
#pragma unroll
    for (int i = 0; i < 4; ++i)
#pragma unroll
        for (int j = 0; j < 4; ++j) acc[i][j] = 0.0f;

    for (int kc = 0; kc < 256; kc += CK) {
        const bool first = (kc < 128);
        const float* Asrc = first ? agg : feat;
        const float* Wsrc = first ? Wl  : Wr;
        const int kb = first ? kc : (kc - 128);

        float4 av = *(const float4*)&Asrc[(size_t)(row0 + sr) * CC + kb + sq * 4];
        At[sq * 4 + 0][sr] = av.x;
        At[sq * 4 + 1][sr] = av.y;
        At[sq * 4 + 2][sr] = av.z;
        At[sq * 4 + 3][sr] = av.w;

#pragma unroll
        for (int j = 0; j < 4; ++j) {
            int lin = t + j * 256;
            int c   = lin >> 3;
            int q   = lin & 7;
            float4 wv = *(const float4*)&Wsrc[c * CC + kb + q * 4];
            Wt[q * 4 + 0][c] = wv.x;
            Wt[q * 4 + 1][c] = wv.y;
            Wt[q * 4 + 2][c] = wv.z;
            Wt[q * 4 + 3][c] = wv.w;
        }
        __syncthreads();

#pragma unroll
        for (int kk = 0; kk < CK; ++kk) {
            float4 a = *(const float4*)&At[kk][tr * 4];
            float4 w = *(const float4*)&Wt[kk][tc * 4];
            acc[0][0] += a.x * w.x; acc[0][1] += a.x * w.y; acc[0][2] += a.x * w.z; acc[0][3] += a.x * w.w;
            acc[1][0] += a.y * w.x; acc[1][1] += a.y * w.y; acc[1][2] += a.y * w.z; acc[1][3] += a.y * w.w;
            acc[2][0] += a.z * w.x; acc[2][1] += a.z * w.y; acc[2][2] += a.z * w.z; acc[2][3] += a.z * w.w;
            acc[3][0] += a.w * w.x; acc[3][1] += a.w * w.y; acc[3][2] += a.w * w.z; acc[3][3] += a.w * w.w;
        }
        __syncthreads();
    }

    const float4 bv = *(const float4*)&bias[tc * 4];
#pragma unroll
    for (int i = 0; i < 4; ++i) {
        const int r = row0 + tr * 4 + i;
        float4 o;
        o.x = acc[i][0] + bv.x;
        o.y = acc[i][1] + bv.y;
        o.z = acc[i][2] + bv.z;
        o.w = acc[i][3] + bv.w;
        if (SIGMOID) {
            o.x = 1.0f / (1.0f + __expf(-o.x));
            o.y = 1.0f / (1.0f + __expf(-o.y));
            o.z = 1.0f / (1.0f + __expf(-o.z));
            o.w = 1.0f / (1.0f + __expf(-o.w));
        }
        *(float4*)&out[(size_t)r * CC + tc * 4] = o;
    }
}

// ---------------- launch ----------------

extern "C" void kernel_launch(void* const* d_in, const int* in_sizes, int n_in,
                              void* d_out, int out_size, void* d_ws, size_t ws_size,
                              hipStream_t stream) {
    const float* x   = (const float*)d_in[0];
    const int*   ei  = (const int*)d_in[1];
    const float* W1l = (const float*)d_in[2];
    const float* b1l = (const float*)d_in[3];
    const float* W1r = (const float*)d_in[4];
    const float* W2l = (const float*)d_in[5];
    const float* b2l = (const float*)d_in[6];
    const float* W2r = (const float*)d_in[7];
    float* out = (float*)d_out;

    const int* src = ei;        // edge_index[0]
    const int* dst = ei + NE;   // edge_index[1]

    // workspace layout (agg kept 16B-aligned: ints before it total 4*NN+4+NE)
    int*   cnt    = (int*)d_ws;              // NN
    int*   rowptr = cnt + NN;                // NN+4 (3 pad)
    int*   cursor = rowptr + NN + 4;         // NN
    int*   col    = cursor + NN;             // NE
    float* inv    = (float*)(col + NE);      // NN
    float* agg    = inv + NN;                // NN*CC
    float* h      = out;                     // layer-1 activations live in d_out

    // zero cnt + rowptr + cursor in one shot
    hipMemsetAsync(d_ws, 0, (size_t)(3 * NN + 4) * sizeof(int), stream);

    // CSR build (shared by both layers)
    degree_kernel<<<(NE + 255) / 256, 256, 0, stream>>>(dst, cnt);
    scan_kernel<<<1, 1024, 0, stream>>>(cnt, rowptr);
    fill_kernel<<<(NE + 255) / 256, 256, 0, stream>>>(src, dst, rowptr, cursor, col);
    inv_kernel<<<(NN + 255) / 256, 256, 0, stream>>>(rowptr, inv);

    // layer 1
    gather_kernel<<<(NN * 64) / 256, 256, 0, stream>>>(x, rowptr, col, inv, agg);
    sage_gemm_kernel<true><<<NN / 32, 256, 0, stream>>>(agg, x, W1l, W1r, b1l, h);

    // layer 2
    gather_kernel<<<(NN * 64) / 256, 256, 0, stream>>>(h, rowptr, col, inv, agg);
    sage_gemm_kernel<false><<<NN / 32, 256, 0, stream>>>(agg, h, W2l, W2r, b2l, out);
}

// Round 3
// 429.086 us; speedup vs baseline: 5.6421x; 1.5812x over previous
//
#include <hip/hip_runtime.h>
#include <math.h>

#define NN 100000
#define NE 625000
#define CC 128

typedef __attribute__((ext_vector_type(8))) short bf16x8;
typedef __attribute__((ext_vector_type(4))) float f32x4;

__device__ __forceinline__ unsigned short f2b(float f) {
    unsigned int u = __float_as_uint(f);
    unsigned int r = (u + 0x7FFFu + ((u >> 16) & 1u)) >> 16;
    return (unsigned short)r;
}
__device__ __forceinline__ float b2f(unsigned int h) {
    return __uint_as_float(h << 16);
}

// ---------------- CSR build ----------------

__global__ void degree_kernel(const int* __restrict__ dst, int* __restrict__ cnt) {
    int e = blockIdx.x * blockDim.x + threadIdx.x;
    if (e < NE) atomicAdd(&cnt[dst[e]], 1);
}

// phase A: per-block exclusive scan of cnt -> rowptr (block-local), block totals -> bsum
__global__ __launch_bounds__(256) void scanA_kernel(const int* __restrict__ cnt,
                                                    int* __restrict__ rowptr,
                                                    int* __restrict__ bsum) {
    __shared__ int sm[256];
    int t = threadIdx.x;
    int i = blockIdx.x * 256 + t;
    int v = (i < NN) ? cnt[i] : 0;
    sm[t] = v;
    __syncthreads();
    for (int off = 1; off < 256; off <<= 1) {
        int u = (t >= off) ? sm[t - off] : 0;
        __syncthreads();
        sm[t] += u;
        __syncthreads();
    }
    if (i < NN) rowptr[i] = sm[t] - v;           // exclusive within block
    if (t == 255) bsum[blockIdx.x] = sm[255];    // block total
}

// phase B: single small block scans the 391 block sums -> exclusive offsets
__global__ __launch_bounds__(512) void scanB_kernel(int* __restrict__ bsum,
                                                    int* __restrict__ boff,
                                                    int nb) {
    __shared__ int sm[512];
    int t = threadIdx.x;
    int v = (t < nb) ? bsum[t] : 0;
    sm[t] = v;
    __syncthreads();
    for (int off = 1; off < 512; off <<= 1) {
        int u = (t >= off) ? sm[t - off] : 0;
        __syncthreads();
        sm[t] += u;
        __syncthreads();
    }
    if (t < nb) boff[t] = sm[t] - v;             // exclusive
}

// phase C: add block offsets
__global__ __launch_bounds__(256) void scanC_kernel(int* __restrict__ rowptr,
                                                    const int* __restrict__ boff) {
    int i = blockIdx.x * 256 + threadIdx.x;
    if (i < NN) rowptr[i] += boff[blockIdx.x];
    if (i == 0) rowptr[NN] = NE;                 // total is simply E
}

__global__ void fill_kernel(const int* __restrict__ src, const int* __restrict__ dst,
                            const int* __restrict__ rowptr, int* __restrict__ cursor,
                            int* __restrict__ col) {
    int e = blockIdx.x * blockDim.x + threadIdx.x;
    if (e < NE) {
        int d = dst[e];
        int p = atomicAdd(&cursor[d], 1);
        col[rowptr[d] + p] = src[e];
    }
}

__global__ void inv_kernel(const int* __restrict__ rowptr, float* __restrict__ inv) {
    int i = blockIdx.x * blockDim.x + threadIdx.x;
    if (i < NN) {
        int d = rowptr[i + 1] - rowptr[i];
        inv[i] = 1.0f / (float)(d > 0 ? d : 1);
    }
}

// ---------------- weight pack: Wcat[c][k2] bf16, k2 = [Wl row | Wr row] ----------------

__global__ void cvtW_kernel(const float* __restrict__ Wl, const float* __restrict__ Wr,
                            unsigned short* __restrict__ Wcat) {
    int i = blockIdx.x * blockDim.x + threadIdx.x;   // 0..32767
    int c = i >> 8;
    int k = i & 255;
    float v = (k < CC) ? Wl[c * CC + k] : Wr[c * CC + (k - CC)];
    Wcat[i] = f2b(v);
}

// ---------------- gather-aggregate -> bf16 ----------------
// one wave per node, 2 channels per lane; fp32 accumulation, bf16 output.

template<bool IN_FP32>
__global__ void gather_kernel(const void* __restrict__ featv,
                              const int* __restrict__ rowptr,
                              const int* __restrict__ col,
                              const float* __restrict__ inv,
                              unsigned short* __restrict__ aggb) {
    int gtid = blockIdx.x * blockDim.x + threadIdx.x;
    int node = gtid >> 6;
    int lane2 = (gtid & 63) * 2;
    if (node >= NN) return;
    int beg = rowptr[node], end = rowptr[node + 1];
    float sx = 0.0f, sy = 0.0f;
    if (IN_FP32) {
        const float* feat = (const float*)featv;
        for (int j = beg; j < end; ++j) {
            int s = col[j];
            float2 v = *(const float2*)&feat[(size_t)s * CC + lane2];
            sx += v.x; sy += v.y;
        }
    } else {
        const unsigned short* feat = (const unsigned short*)featv;
        for (int j = beg; j < end; ++j) {
            int s = col[j];
            unsigned int u = *(const unsigned int*)&feat[(size_t)s * CC + lane2];
            sx += b2f(u & 0xFFFFu);
            sy += b2f(u >> 16);
        }
    }
    float iv = inv[node];
    unsigned int o = (unsigned int)f2b(sx * iv) | ((unsigned int)f2b(sy * iv) << 16);
    *(unsigned int*)&aggb[(size_t)node * CC + lane2] = o;
}

// ---------------- MFMA SAGE GEMM ----------------
// out[r][c] = act( sum_k2 Acat[r][k2] * Wcat[c][k2] + bias[c] ),
// Acat = [aggb row (bf16) | feat row (fp32 or bf16)], K2 = 256.
// Block 256 thr = 4 waves; block tile 64 rows x 128 cols; wave tile 32x64.
// mfma_f32_16x16x32_bf16: A[m=lane&15][k=(lane>>4)*8+j]; B mirrored; C/D col=lane&15,row=(lane>>4)*4+reg.

template<bool SIGMOID, bool FEAT_FP32, bool OUT_FP32>
__global__ __launch_bounds__(256) void mfma_gemm_kernel(
        const unsigned short* __restrict__ aggb,
        const void* __restrict__ featv,
        const unsigned short* __restrict__ Wcat,
        const float* __restrict__ bias,
        void* __restrict__ outv) {
    const int w    = threadIdx.x >> 6;
    const int lane = threadIdx.x & 63;
    const int row0 = blockIdx.x * 64 + (w >> 1) * 32;
    const int col0 = (w & 1) * 64;
    const int m    = lane & 15;
    const int kq   = lane >> 4;          // 0..3

    f32x4 acc[2][4];
#pragma unroll
    for (int mi = 0; mi < 2; ++mi)
#pragma unroll
        for (int nt = 0; nt < 4; ++nt) acc[mi][nt] = (f32x4)0.0f;

    const int r0 = (row0 + m      < NN) ? (row0 + m)      : (NN - 1);
    const int r1 = (row0 + 16 + m < NN) ? (row0 + 16 + m) : (NN - 1);

#pragma unroll
    for (int ks = 0; ks < 8; ++ks) {
        const int kk = (ks & 3) * 32 + kq * 8;     // offset within the 128-wide half
        bf16x8 a[2];
        if (ks < 4) {
            a[0] = *(const bf16x8*)(aggb + (size_t)r0 * CC + kk);
            a[1] = *(const bf16x8*)(aggb + (size_t)r1 * CC + kk);
        } else if (!FEAT_FP32) {
            const unsigned short* fb = (const unsigned short*)featv;
            a[0] = *(const bf16x8*)(fb + (size_t)r0 * CC + kk);
            a[1] = *(const bf16x8*)(fb + (size_t)r1 * CC + kk);
        } else {
            const float* xf = (const float*)featv;
#pragma unroll
            for (int mi = 0; mi < 2; ++mi) {
                const float* p = xf + (size_t)(mi ? r1 : r0) * CC + kk;
                float4 lo = *(const float4*)p;
                float4 hi = *(const float4*)(p + 4);
                bf16x8 v;
                v[0] = (short)f2b(lo.x); v[1] = (short)f2b(lo.y);
                v[2] = (short)f2b(lo.z); v[3] = (short)f2b(lo.w);
                v[4] = (short)f2b(hi.x); v[5] = (short)f2b(hi.y);
                v[6] = (short)f2b(hi.z); v[7] = (short)f2b(hi.w);
                a[mi] = v;
            }
        }
        const int wk = ks * 32 + kq * 8;
#pragma unroll
        for (int nt = 0; nt < 4; ++nt) {
            const int c = col0 + nt * 16 + m;
            bf16x8 b = *(const bf16x8*)(Wcat + (size_t)c * 256 + wk);
            acc[0][nt] = __builtin_amdgcn_mfma_f32_16x16x32_bf16(a[0], b, acc[0][nt], 0, 0, 0);
            acc[1][nt] = __builtin_amdgcn_mfma_f32_16x16x32_bf16(a[1], b, acc[1][nt], 0, 0, 0);
        }
    }

    // epilogue
#pragma unroll
    for (int mi = 0; mi < 2; ++mi) {
#pragma unroll
        for (int nt = 0; nt < 4; ++nt) {
            const int c = col0 + nt * 16 + m;
            const float bv = bias[c];
#pragma unroll
            for (int i = 0; i < 4; ++i) {
                const int r = row0 + mi * 16 + kq * 4 + i;
                if (r < NN) {
                    float v = acc[mi][nt][i] + bv;
                    if (SIGMOID) v = 1.0f / (1.0f + __expf(-v));
                    if (OUT_FP32) ((float*)outv)[(size_t)r * CC + c] = v;
                    else ((unsigned short*)outv)[(size_t)r * CC + c] = f2b(v);
                }
            }
        }
    }
}

// ---------------- launch ----------------

extern "C" void kernel_launch(void* const* d_in, const int* in_sizes, int n_in,
                              void* d_out, int out_size, void* d_ws, size_t ws_size,
                              hipStream_t stream) {
    const float* x   = (const float*)d_in[0];
    const int*   ei  = (const int*)d_in[1];
    const float* W1l = (const float*)d_in[2];
    const float* b1l = (const float*)d_in[3];
    const float* W1r = (const float*)d_in[4];
    const float* W2l = (const float*)d_in[5];
    const float* b2l = (const float*)d_in[6];
    const float* W2r = (const float*)d_in[7];
    float* out = (float*)d_out;

    const int* src = ei;        // edge_index[0]
    const int* dst = ei + NE;   // edge_index[1]

    const int NB = (NN + 255) / 256;    // 391 scan blocks

    // workspace layout (ints first; bf16 region stays 16B-aligned)
    int* cnt    = (int*)d_ws;                 // NN
    int* cursor = cnt + NN;                   // NN
    int* rowptr = cursor + NN;                // NN+4 (3 pad)
    int* bsum   = rowptr + NN + 4;            // 512
    int* boff   = bsum + 512;                 // 512
    int* col    = boff + 512;                 // NE
    float* inv  = (float*)(col + NE);         // NN
    unsigned short* Wcat1 = (unsigned short*)(inv + NN);       // 128*256
    unsigned short* Wcat2 = Wcat1 + 128 * 256;                 // 128*256
    unsigned short* aggb  = Wcat2 + 128 * 256;                 // NN*CC
    unsigned short* hb    = aggb + (size_t)NN * CC;            // NN*CC

    // zero cnt + cursor
    hipMemsetAsync(d_ws, 0, (size_t)(2 * NN) * sizeof(int), stream);

    // CSR build (shared by both layers)
    degree_kernel<<<(NE + 255) / 256, 256, 0, stream>>>(dst, cnt);
    scanA_kernel<<<NB, 256, 0, stream>>>(cnt, rowptr, bsum);
    scanB_kernel<<<1, 512, 0, stream>>>(bsum, boff, NB);
    scanC_kernel<<<NB, 256, 0, stream>>>(rowptr, boff);
    fill_kernel<<<(NE + 255) / 256, 256, 0, stream>>>(src, dst, rowptr, cursor, col);
    inv_kernel<<<(NN + 255) / 256, 256, 0, stream>>>(rowptr, inv);

    // weight packing
    cvtW_kernel<<<128, 256, 0, stream>>>(W1l, W1r, Wcat1);
    cvtW_kernel<<<128, 256, 0, stream>>>(W2l, W2r, Wcat2);

    const int GEMM_BLOCKS = (NN + 63) / 64;   // 1563

    // layer 1: gather x (fp32) -> aggb bf16; GEMM (feat fp32 cvt inline) -> hb bf16 (sigmoid)
    gather_kernel<true><<<(NN * 64) / 256, 256, 0, stream>>>(x, rowptr, col, inv, aggb);
    mfma_gemm_kernel<true, true, false><<<GEMM_BLOCKS, 256, 0, stream>>>(aggb, x, Wcat1, b1l, hb);

    // layer 2: gather hb (bf16) -> aggb bf16; GEMM -> d_out fp32
    gather_kernel<false><<<(NN * 64) / 256, 256, 0, stream>>>(hb, rowptr, col, inv, aggb);
    mfma_gemm_kernel<false, false, true><<<GEMM_BLOCKS, 256, 0, stream>>>(aggb, hb, Wcat2, b2l, out);
}

// Round 4
// 375.724 us; speedup vs baseline: 6.4434x; 1.1420x over previous
//
#include <hip/hip_runtime.h>
#include <math.h>

#define NN 100000
#define NE 625000
#define CC 128

typedef __attribute__((ext_vector_type(8))) short bf16x8;
typedef __attribute__((ext_vector_type(4))) float f32x4;

__device__ __forceinline__ unsigned short f2b(float f) {
    unsigned int u = __float_as_uint(f);
    unsigned int r = (u + 0x7FFFu + ((u >> 16) & 1u)) >> 16;
    return (unsigned short)r;
}
__device__ __forceinline__ float b2f(unsigned int h) {
    return __uint_as_float(h << 16);
}

// ---------------- CSR build ----------------

__global__ void degree_kernel(const int* __restrict__ dst, int* __restrict__ cnt) {
    int e = blockIdx.x * blockDim.x + threadIdx.x;
    if (e < NE) atomicAdd(&cnt[dst[e]], 1);
}

__global__ __launch_bounds__(256) void scanA_kernel(const int* __restrict__ cnt,
                                                    int* __restrict__ rowptr,
                                                    int* __restrict__ bsum) {
    __shared__ int sm[256];
    int t = threadIdx.x;
    int i = blockIdx.x * 256 + t;
    int v = (i < NN) ? cnt[i] : 0;
    sm[t] = v;
    __syncthreads();
    for (int off = 1; off < 256; off <<= 1) {
        int u = (t >= off) ? sm[t - off] : 0;
        __syncthreads();
        sm[t] += u;
        __syncthreads();
    }
    if (i < NN) rowptr[i] = sm[t] - v;
    if (t == 255) bsum[blockIdx.x] = sm[255];
}

__global__ __launch_bounds__(512) void scanB_kernel(int* __restrict__ bsum,
                                                    int* __restrict__ boff,
                                                    int nb) {
    __shared__ int sm[512];
    int t = threadIdx.x;
    int v = (t < nb) ? bsum[t] : 0;
    sm[t] = v;
    __syncthreads();
    for (int off = 1; off < 512; off <<= 1) {
        int u = (t >= off) ? sm[t - off] : 0;
        __syncthreads();
        sm[t] += u;
        __syncthreads();
    }
    if (t < nb) boff[t] = sm[t] - v;
}

__global__ __launch_bounds__(256) void scanC_kernel(int* __restrict__ rowptr,
                                                    const int* __restrict__ boff) {
    int i = blockIdx.x * 256 + threadIdx.x;
    if (i < NN) rowptr[i] += boff[blockIdx.x];
    if (i == 0) rowptr[NN] = NE;
}

__global__ void fill_kernel(const int* __restrict__ src, const int* __restrict__ dst,
                            const int* __restrict__ rowptr, int* __restrict__ cursor,
                            int* __restrict__ col) {
    int e = blockIdx.x * blockDim.x + threadIdx.x;
    if (e < NE) {
        int d = dst[e];
        int p = atomicAdd(&cursor[d], 1);
        col[rowptr[d] + p] = src[e];
    }
}

// ---------------- x -> bf16 table ----------------

__global__ __launch_bounds__(256) void cvtX_kernel(const float* __restrict__ x,
                                                   unsigned short* __restrict__ xb) {
    size_t i = ((size_t)blockIdx.x * 256 + threadIdx.x) * 4;   // 12.8M elements / 4
    float4 v = *(const float4*)&x[i];
    ushort2 lo = { f2b(v.x), f2b(v.y) };
    ushort2 hi = { f2b(v.z), f2b(v.w) };
    *(ushort2*)&xb[i]     = lo;
    *(ushort2*)&xb[i + 2] = hi;
}

// ---------------- weight pack: Wcat[c][k2] bf16, k2 = [Wl row | Wr row] ----------------

__global__ void cvtW_kernel(const float* __restrict__ Wl, const float* __restrict__ Wr,
                            unsigned short* __restrict__ Wcat) {
    int i = blockIdx.x * blockDim.x + threadIdx.x;
    int c = i >> 8;
    int k = i & 255;
    float v = (k < CC) ? Wl[c * CC + k] : Wr[c * CC + (k - CC)];
    Wcat[i] = f2b(v);
}

// ---------------- gather-aggregate (bf16 in, bf16 out) ----------------
// one wave per node; two 32-lane halves walk alternate edges, 4 ch/lane (8B loads);
// combine via shfl_xor(32); inv folded in from rowptr.

__global__ __launch_bounds__(256) void gather_kernel(const unsigned short* __restrict__ feat,
                                                     const int* __restrict__ rowptr,
                                                     const int* __restrict__ col,
                                                     unsigned short* __restrict__ aggb) {
    int gtid = blockIdx.x * blockDim.x + threadIdx.x;
    int node = gtid >> 6;
    int lane = gtid & 63;
    int half = lane >> 5;
    int c4   = (lane & 31) * 4;
    if (node >= NN) return;
    int beg = rowptr[node], end = rowptr[node + 1];
    float s0 = 0.0f, s1 = 0.0f, s2 = 0.0f, s3 = 0.0f;
    for (int j = beg + half; j < end; j += 2) {
        int s = col[j];
        uint2 u = *(const uint2*)&feat[(size_t)s * CC + c4];
        s0 += b2f(u.x & 0xFFFFu); s1 += b2f(u.x >> 16);
        s2 += b2f(u.y & 0xFFFFu); s3 += b2f(u.y >> 16);
    }
    s0 += __shfl_xor(s0, 32);
    s1 += __shfl_xor(s1, 32);
    s2 += __shfl_xor(s2, 32);
    s3 += __shfl_xor(s3, 32);
    if (half == 0) {
        int d = end - beg;
        float iv = 1.0f / (float)(d > 0 ? d : 1);
        uint2 o;
        o.x = (unsigned int)f2b(s0 * iv) | ((unsigned int)f2b(s1 * iv) << 16);
        o.y = (unsigned int)f2b(s2 * iv) | ((unsigned int)f2b(s3 * iv) << 16);
        *(uint2*)&aggb[(size_t)node * CC + c4] = o;
    }
}

// ---------------- MFMA SAGE GEMM ----------------
// out[r][c] = act( sum_k2 Acat[r][k2] * Wcat[c][k2] + bias[c] ),
// Acat = [aggb row | featb row] (both bf16), K2 = 256.
// Block 256 thr = 4 waves; block tile 64 rows x 128 cols; wave tile 32x64.

template<bool SIGMOID, bool OUT_FP32>
__global__ __launch_bounds__(256) void mfma_gemm_kernel(
        const unsigned short* __restrict__ aggb,
        const unsigned short* __restrict__ featb,
        const unsigned short* __restrict__ Wcat,
        const float* __restrict__ bias,
        void* __restrict__ outv) {
    const int w    = threadIdx.x >> 6;
    const int lane = threadIdx.x & 63;
    const int row0 = blockIdx.x * 64 + (w >> 1) * 32;
    const int col0 = (w & 1) * 64;
    const int m    = lane & 15;
    const int kq   = lane >> 4;

    f32x4 acc[2][4];
#pragma unroll
    for (int mi = 0; mi < 2; ++mi)
#pragma unroll
        for (int nt = 0; nt < 4; ++nt) acc[mi][nt] = (f32x4)0.0f;

    const int r0 = (row0 + m      < NN) ? (row0 + m)      : (NN - 1);
    const int r1 = (row0 + 16 + m < NN) ? (row0 + 16 + m) : (NN - 1);

#pragma unroll
    for (int ks = 0; ks < 8; ++ks) {
        const int kk = (ks & 3) * 32 + kq * 8;
        const unsigned short* A = (ks < 4) ? aggb : featb;
        bf16x8 a0 = *(const bf16x8*)(A + (size_t)r0 * CC + kk);
        bf16x8 a1 = *(const bf16x8*)(A + (size_t)r1 * CC + kk);
        const int wk = ks * 32 + kq * 8;
#pragma unroll
        for (int nt = 0; nt < 4; ++nt) {
            const int c = col0 + nt * 16 + m;
            bf16x8 b = *(const bf16x8*)(Wcat + (size_t)c * 256 + wk);
            acc[0][nt] = __builtin_amdgcn_mfma_f32_16x16x32_bf16(a0, b, acc[0][nt], 0, 0, 0);
            acc[1][nt] = __builtin_amdgcn_mfma_f32_16x16x32_bf16(a1, b, acc[1][nt], 0, 0, 0);
        }
    }

#pragma unroll
    for (int mi = 0; mi < 2; ++mi) {
#pragma unroll
        for (int nt = 0; nt < 4; ++nt) {
            const int c = col0 + nt * 16 + m;
            const float bv = bias[c];
#pragma unroll
            for (int i = 0; i < 4; ++i) {
                const int r = row0 + mi * 16 + kq * 4 + i;
                if (r < NN) {
                    float v = acc[mi][nt][i] + bv;
                    if (SIGMOID) v = 1.0f / (1.0f + __expf(-v));
                    if (OUT_FP32) ((float*)outv)[(size_t)r * CC + c] = v;
                    else ((unsigned short*)outv)[(size_t)r * CC + c] = f2b(v);
                }
            }
        }
    }
}

// ---------------- launch ----------------

extern "C" void kernel_launch(void* const* d_in, const int* in_sizes, int n_in,
                              void* d_out, int out_size, void* d_ws, size_t ws_size,
                              hipStream_t stream) {
    const float* x   = (const float*)d_in[0];
    const int*   ei  = (const int*)d_in[1];
    const float* W1l = (const float*)d_in[2];
    const float* b1l = (const float*)d_in[3];
    const float* W1r = (const float*)d_in[4];
    const float* W2l = (const float*)d_in[5];
    const float* b2l = (const float*)d_in[6];
    const float* W2r = (const float*)d_in[7];
    float* out = (float*)d_out;

    const int* src = ei;
    const int* dst = ei + NE;

    const int NB = (NN + 255) / 256;    // 391

    // workspace layout
    int* cnt    = (int*)d_ws;                 // NN
    int* cursor = cnt + NN;                   // NN
    int* rowptr = cursor + NN;                // NN+4 (3 pad)
    int* bsum   = rowptr + NN + 4;            // 512
    int* boff   = bsum + 512;                 // 512
    int* col    = boff + 512;                 // NE
    unsigned short* Wcat1 = (unsigned short*)(col + NE);       // 128*256
    unsigned short* Wcat2 = Wcat1 + 128 * 256;                 // 128*256
    unsigned short* xb    = Wcat2 + 128 * 256;                 // NN*CC
    unsigned short* aggb  = xb + (size_t)NN * CC;              // NN*CC
    unsigned short* hb    = aggb + (size_t)NN * CC;            // NN*CC

    hipMemsetAsync(d_ws, 0, (size_t)(2 * NN) * sizeof(int), stream);

    // CSR build (shared by both layers)
    degree_kernel<<<(NE + 255) / 256, 256, 0, stream>>>(dst, cnt);
    scanA_kernel<<<NB, 256, 0, stream>>>(cnt, rowptr, bsum);
    scanB_kernel<<<1, 512, 0, stream>>>(bsum, boff, NB);
    scanC_kernel<<<NB, 256, 0, stream>>>(rowptr, boff);
    fill_kernel<<<(NE + 255) / 256, 256, 0, stream>>>(src, dst, rowptr, cursor, col);

    // dtype prep
    cvtX_kernel<<<(NN * CC / 4 + 255) / 256, 256, 0, stream>>>(x, xb);
    cvtW_kernel<<<128, 256, 0, stream>>>(W1l, W1r, Wcat1);
    cvtW_kernel<<<128, 256, 0, stream>>>(W2l, W2r, Wcat2);

    const int GEMM_BLOCKS = (NN + 63) / 64;   // 1563

    // layer 1
    gather_kernel<<<(NN * 64) / 256, 256, 0, stream>>>(xb, rowptr, col, aggb);
    mfma_gemm_kernel<true, false><<<GEMM_BLOCKS, 256, 0, stream>>>(aggb, xb, Wcat1, b1l, hb);

    // layer 2
    gather_kernel<<<(NN * 64) / 256, 256, 0, stream>>>(hb, rowptr, col, aggb);
    mfma_gemm_kernel<false, true><<<GEMM_BLOCKS, 256, 0, stream>>>(aggb, hb, Wcat2, b2l, out);
}